// Round 2
// baseline (9692.926 us; speedup 1.0000x reference)
//
#include <hip/hip_runtime.h>
#include <stdint.h>
#include <stddef.h>

// Persistent-LSTM design for T=1024, B=64, E=H=512 (all fp32 in/out).
//
//  - 4 batch groups x 16 batches (MFMA M=16); 32 blocks per group, each block
//    owns a 16-wide j-slice => 64 z-columns (4 gates x 16 cols). 128 blocks.
//  - Gate weights held in registers as bf16 MFMA B-fragments, hi+lo split
//    (W ~= hi + lo in bf16 pairs => effectively fp32 weights).
//  - x operand also hi/lo split; h operand single bf16 (error ~2e-4/step).
//  - h exchange between the 32 blocks of a group goes through LLC with
//    agent-scope atomics (per-XCD L2s are not coherent); one sense flag per
//    block per step, release-store after wave-0 publishes its h slice.
//  - c state lives in thread registers (thread tid owns (b,j)=(tid>>4,tid&15)).
//  - d_ws layout: [0,128KB) h double buffer bf16 [2][64][512];
//                 [128KB, 136KB) flags, 128 slots x 64B. Poison 0xAA reads as
//                 a negative int => safe "not arrived yet".
//
// R1 fix: h-pull loop only covered 256 of 512 columns (it<4, c8=idx&63) —
// upper half of h operand was stale x data => absmax ~1.0. Now it<8,
// r=idx>>7, c8=idx&127. Also added acquire fence after flag poll.

#define Tn 1024
#define Bn 64
#define Hn 512
#define En 512
#define NGROUP 4
#define NJBLK 32
#define NBLOCK (NGROUP * NJBLK)

using bf16x8 = __attribute__((ext_vector_type(8))) __bf16;
using f32x4  = __attribute__((ext_vector_type(4))) float;
using u16x8  = __attribute__((ext_vector_type(8))) unsigned short;
using u16x4  = __attribute__((ext_vector_type(4))) unsigned short;

__device__ __forceinline__ unsigned short f2bf(float f) {
    unsigned u = __builtin_bit_cast(unsigned, f);
    unsigned r = (u + 0x7FFFu + ((u >> 16) & 1u)) >> 16;
    return (unsigned short)r;
}
__device__ __forceinline__ float bf2f(unsigned short b) {
    unsigned u = ((unsigned)b) << 16;
    return __builtin_bit_cast(float, u);
}

__global__ __launch_bounds__(256, 1) void lstm_persistent(
    const float* __restrict__ embeds,
    const float* __restrict__ wx0, const float* __restrict__ wh0, const float* __restrict__ bs0,
    const float* __restrict__ wx1, const float* __restrict__ wh1, const float* __restrict__ bs1,
    const float* __restrict__ wx2, const float* __restrict__ wh2, const float* __restrict__ bs2,
    const float* __restrict__ wx3, const float* __restrict__ wh3, const float* __restrict__ bs3,
    float* __restrict__ out, void* __restrict__ ws)
{
    __shared__ unsigned short Ahi[16][520];   // A operand (x hi, then h), +8 pad
    __shared__ unsigned short Alo[16][520];   // A operand (x lo)
    __shared__ float exch[4][16][17];         // gate exchange g/i/f/o
    __shared__ unsigned short hstage[16][16]; // packed h_new slice (bf16)

    const int tid  = threadIdx.x;
    const int wav  = tid >> 6;     // wave = gate (0=g,1=i,2=f,3=o)
    const int lane = tid & 63;
    const int q    = lane >> 4;
    const int n    = lane & 15;

    const int gid = blockIdx.x / NJBLK;  // batch group
    const int kid = blockIdx.x % NJBLK;  // j-slice
    const int b0  = gid * 16;
    const int j0  = kid * 16;

    unsigned short* hbuf = (unsigned short*)ws;                 // [2][64][512] bf16
    int* flags  = (int*)((char*)ws + (size_t)2 * Bn * Hn * 2);  // 128 x 16 ints
    int* gflags = flags + gid * NJBLK * 16;
    int* myflag = gflags + kid * 16;

    const float* wxp = (wav == 0) ? wx0 : (wav == 1) ? wx1 : (wav == 2) ? wx2 : wx3;
    const float* whp = (wav == 0) ? wh0 : (wav == 1) ? wh1 : (wav == 2) ? wh2 : wh3;
    const float* bsp = (wav == 0) ? bs0 : (wav == 1) ? bs1 : (wav == 2) ? bs2 : bs3;

    // ---- publish h_0 = 0 (wave 0 only so the release below covers it) ----
    if (tid < 64) {
        int r = tid >> 2, cq = tid & 3;
        unsigned long long* dst =
            (unsigned long long*)&hbuf[((size_t)(0 * Bn + b0 + r)) * Hn + j0 + cq * 4];
        __hip_atomic_store(dst, 0ull, __ATOMIC_RELAXED, __HIP_MEMORY_SCOPE_AGENT);
    }
    __syncthreads();
    if (tid == 0)
        __hip_atomic_store(myflag, 1, __ATOMIC_RELEASE, __HIP_MEMORY_SCOPE_AGENT);

    // ---- preload weight fragments into registers (bf16 hi/lo) ----
    // B-frag layout for mfma_f32_16x16x32_bf16: lane holds B[k=q*8+i][n=lane&15]
    bf16x8 WXhi[16], WXlo[16], WHhi[16], WHlo[16];
    const int col = j0 + n;
    #pragma unroll
    for (int kk = 0; kk < 16; ++kk) {
        u16x8 xh, xl, hh, hl;
        #pragma unroll
        for (int i = 0; i < 8; ++i) {
            int k = kk * 32 + q * 8 + i;
            float w  = wxp[(size_t)k * Hn + col];
            unsigned short hi = f2bf(w);
            xh[i] = hi;
            xl[i] = f2bf(w - bf2f(hi));
            w  = whp[(size_t)k * Hn + col];
            hi = f2bf(w);
            hh[i] = hi;
            hl[i] = f2bf(w - bf2f(hi));
        }
        WXhi[kk] = __builtin_bit_cast(bf16x8, xh);
        WXlo[kk] = __builtin_bit_cast(bf16x8, xl);
        WHhi[kk] = __builtin_bit_cast(bf16x8, hh);
        WHlo[kk] = __builtin_bit_cast(bf16x8, hl);
    }
    const float bias_l = bsp[col];
    float c_state = 0.f;   // thread owns (b,j) = (tid>>4, tid&15)

    for (int t = 1; t <= Tn; ++t) {
        const int tau = t - 1;

        // ---- stage x_tau[16,512] fp32 -> bf16 hi/lo in LDS (coalesced f4) ----
        #pragma unroll
        for (int it = 0; it < 8; ++it) {
            int idx = tid + it * 256;          // 0..2047
            int r = idx >> 7, c4 = idx & 127;  // row(batch), float4 index
            const float4* src =
                (const float4*)(embeds + ((size_t)tau * Bn + b0 + r) * En) + c4;
            float4 v = *src;
            float fs[4] = {v.x, v.y, v.z, v.w};
            u16x4 vh, vl;
            #pragma unroll
            for (int e = 0; e < 4; ++e) {
                unsigned short hb = f2bf(fs[e]);
                vh[e] = hb;
                vl[e] = f2bf(fs[e] - bf2f(hb));
            }
            *(u16x4*)&Ahi[r][c4 * 4] = vh;
            *(u16x4*)&Alo[r][c4 * 4] = vl;
        }
        __syncthreads();

        f32x4 acc, acc2;
        acc[0] = bias_l; acc[1] = bias_l; acc[2] = bias_l; acc[3] = bias_l;
        acc2[0] = 0.f; acc2[1] = 0.f; acc2[2] = 0.f; acc2[3] = 0.f;

        // ---- x part: (xhi+xlo) @ (Whi+Wlo), dropping lo*lo ----
        #pragma unroll
        for (int kk = 0; kk < 16; ++kk) {
            bf16x8 ah = __builtin_bit_cast(bf16x8, *(const u16x8*)&Ahi[n][kk * 32 + q * 8]);
            bf16x8 al = __builtin_bit_cast(bf16x8, *(const u16x8*)&Alo[n][kk * 32 + q * 8]);
            acc  = __builtin_amdgcn_mfma_f32_16x16x32_bf16(ah, WXhi[kk], acc, 0, 0, 0);
            acc2 = __builtin_amdgcn_mfma_f32_16x16x32_bf16(ah, WXlo[kk], acc2, 0, 0, 0);
            acc2 = __builtin_amdgcn_mfma_f32_16x16x32_bf16(al, WXhi[kk], acc2, 0, 0, 0);
        }

        // ---- wait for all 32 peers to have published h_{t-1} ----
        if (wav == 0) {
            const int* fl = gflags + (lane & 31) * 16;
            for (;;) {
                int v = __hip_atomic_load(fl, __ATOMIC_RELAXED, __HIP_MEMORY_SCOPE_AGENT);
                if (__all(v >= t)) break;
            }
            __builtin_amdgcn_fence(__ATOMIC_ACQUIRE, "agent");
        }
        __syncthreads();   // also fences: x-MFMA LDS reads done before h overwrite

        // ---- pull h_{t-1}[16,512] bf16 through LLC into Ahi ----
        const unsigned short* hsrc =
            hbuf + (size_t)((t - 1) & 1) * Bn * Hn + (size_t)b0 * Hn;
        #pragma unroll
        for (int it = 0; it < 8; ++it) {
            int idx = tid + it * 256;           // 0..2047 (16 rows x 128 qwords)
            int r = idx >> 7, c8 = idx & 127;
            unsigned long long v = __hip_atomic_load(
                (const unsigned long long*)(hsrc + (size_t)r * Hn + c8 * 4),
                __ATOMIC_RELAXED, __HIP_MEMORY_SCOPE_AGENT);
            *(u16x4*)&Ahi[r][c8 * 4] = __builtin_bit_cast(u16x4, v);
        }
        __syncthreads();

        // ---- h part: h @ (Whi+Wlo) ----
        #pragma unroll
        for (int kk = 0; kk < 16; ++kk) {
            bf16x8 a = __builtin_bit_cast(bf16x8, *(const u16x8*)&Ahi[n][kk * 32 + q * 8]);
            acc  = __builtin_amdgcn_mfma_f32_16x16x32_bf16(a, WHhi[kk], acc, 0, 0, 0);
            acc2 = __builtin_amdgcn_mfma_f32_16x16x32_bf16(a, WHlo[kk], acc2, 0, 0, 0);
        }

        // ---- activations; D layout: row=(q*4+r)=batch, col=n=j ----
        #pragma unroll
        for (int r = 0; r < 4; ++r) {
            float zv  = acc[r] + acc2[r];
            float arg = (wav == 0) ? -2.f * zv : -zv;
            float s   = __builtin_amdgcn_rcpf(1.f + __expf(arg));
            float act = (wav == 0) ? (2.f * s - 1.f) : s;
            exch[wav][q * 4 + r][n] = act;
        }
        __syncthreads();

        // ---- per-thread cell update; write output ----
        {
            int b = tid >> 4, j = tid & 15;
            float g  = exch[0][b][j];
            float ig = exch[1][b][j];
            float fg = exch[2][b][j];
            float og = exch[3][b][j];
            c_state = g * ig + c_state * fg;
            float e2 = __expf(-2.f * c_state);
            float th = 2.f * __builtin_amdgcn_rcpf(1.f + e2) - 1.f;
            float hv = th * og;
            out[((size_t)tau * Bn + b0 + b) * Hn + j0 + j] = hv;
            hstage[b][j] = f2bf(hv);
        }
        __syncthreads();

        // ---- publish h_t slice (wave 0) + release flag ----
        if (tid < 64) {
            int r = tid >> 2, cq = tid & 3;
            unsigned long long v =
                __builtin_bit_cast(unsigned long long, *(const u16x4*)&hstage[r][cq * 4]);
            unsigned long long* dst =
                (unsigned long long*)&hbuf[((size_t)((t & 1) * Bn + b0 + r)) * Hn + j0 + cq * 4];
            __hip_atomic_store(dst, v, __ATOMIC_RELAXED, __HIP_MEMORY_SCOPE_AGENT);
        }
        if (tid == 0)
            __hip_atomic_store(myflag, t + 1, __ATOMIC_RELEASE, __HIP_MEMORY_SCOPE_AGENT);
    }
}

extern "C" void kernel_launch(void* const* d_in, const int* in_sizes, int n_in,
                              void* d_out, int out_size, void* d_ws, size_t ws_size,
                              hipStream_t stream) {
    // setup_inputs order: embeds, (w_gx,w_gh,bias_g), (w_ix,w_ih,bias_i),
    //                     (w_fx,w_fh,bias_f), (w_ox,w_oh,bias_o)
    lstm_persistent<<<dim3(NBLOCK), dim3(256), 0, stream>>>(
        (const float*)d_in[0],
        (const float*)d_in[1], (const float*)d_in[2], (const float*)d_in[3],
        (const float*)d_in[4], (const float*)d_in[5], (const float*)d_in[6],
        (const float*)d_in[7], (const float*)d_in[8], (const float*)d_in[9],
        (const float*)d_in[10], (const float*)d_in[11], (const float*)d_in[12],
        (float*)d_out, d_ws);
}